// Round 7
// baseline (214.946 us; speedup 1.0000x reference)
//
#include <hip/hip_runtime.h>

// YOLOv1 loss: 802816 rows x 30 f32, two tensors, scalar out.
// R7: R4 (serial loads) == R6 (30 batched loads) == ~74 us proved the
// plateau is REQUEST-RATE bound, not latency: lane-stride-120B loads make
// every wave instruction touch 64 distinct cache lines -> 30 line-requests
// per row, ~94K/CU, ~1/cycle TA throughput. Fix: 2 rows/thread via
// global_load_dwordx4 (240B/thread, 16B aligned) -> 15 requests/row.
// Loads stay in one asm block (30 dwordx4 + vmcnt(0)) so the register
// allocator cannot re-serialize them; launch_bounds(256,2) for ~180 VGPRs.

#define COLS 30
#define NB   1568              // 802816 rows / 512 rows per K1 block

// ---------------- per-row math on named scalars (bit-exact) ---------------
#define ROW_MATH_BODY                                                        \
    const float C = 1.0f / 7.0f;                                             \
    float conf = b2.x;                    /* T[4], exactly 0.0 or 1.0 */     \
    coord = (conf == 1.0f);                                                  \
    noo = 0.0f;                                                              \
    if (conf == 0.0f) {                                                      \
        float d4_ = a2.x - conf;                                             \
        float d9_ = a4.y - b4.y;                                             \
        noo = d4_ * d4_ + d9_ * d9_;                                         \
    }                                                                        \
    float T0 = b0.x, T1 = b0.y, T2v = b1.x, T3 = b1.y;                       \
    float tb0 = T0 * T0, tb1 = T1 * T1, tb2 = T2v * T2v, tb3 = T3 * T3;      \
    float tax = tb0 * C - tb2, tay = tb1 * C - tb3;                          \
    float tbx = tax * C + tb2, tby = tay * C + tb3;                          \
    float areaT = (tbx - tax) * (tby - tay);                                 \
    float pax0 = a0.x * C - a1.x, pay0 = a0.y * C - a1.y;                    \
    float pbx0 = pax0 * C + a1.x, pby0 = pay0 * C + a1.y;                    \
    float pax1 = a2.y * C - a3.y, pay1 = a3.x * C - a4.x;                    \
    float pbx1 = pax1 * C + a3.y, pby1 = pay1 * C + a4.x;                    \
    float ltx = fmaxf(pax0, tax), lty = fmaxf(pay0, tay);                    \
    float rbx = fminf(pbx0, tbx), rby = fminf(pby0, tby);                    \
    float wx = fmaxf(rbx - ltx, 0.0f), wy = fmaxf(rby - lty, 0.0f);          \
    float inter = wx * wy;                                                   \
    float areaP = (pbx0 - pax0) * (pby0 - pay0);                             \
    float iou0 = inter / (areaP + areaT - inter);                            \
    ltx = fmaxf(pax1, tax); lty = fmaxf(pay1, tay);                          \
    rbx = fminf(pbx1, tbx); rby = fminf(pby1, tby);                          \
    wx = fmaxf(rbx - ltx, 0.0f); wy = fmaxf(rby - lty, 0.0f);                \
    inter = wx * wy;                                                         \
    areaP = (pbx1 - pax1) * (pby1 - pay1);                                   \
    float iou1 = inter / (areaP + areaT - inter);                            \
    int idx = (iou1 > iou0) ? 1 : 0;      /* argmax, first on ties */        \
    float sx = idx ? a2.y : a0.x;                                            \
    float sy = idx ? a3.x : a0.y;                                            \
    float sw = idx ? a3.y : a1.x;                                            \
    float sh = idx ? a4.x : a1.y;                                            \
    float best = b5.x, pc = a5.x;         /* class argmax, strict > */       \
    CLS_STEP(b5.y,  a5.y)  CLS_STEP(b6.x,  a6.x)  CLS_STEP(b6.y,  a6.y)      \
    CLS_STEP(b7.x,  a7.x)  CLS_STEP(b7.y,  a7.y)  CLS_STEP(b8.x,  a8.x)      \
    CLS_STEP(b8.y,  a8.y)  CLS_STEP(b9.x,  a9.x)  CLS_STEP(b9.y,  a9.y)      \
    CLS_STEP(b10.x, a10.x) CLS_STEP(b10.y, a10.y) CLS_STEP(b11.x, a11.x)     \
    CLS_STEP(b11.y, a11.y) CLS_STEP(b12.x, a12.x) CLS_STEP(b12.y, a12.y)     \
    CLS_STEP(b13.x, a13.x) CLS_STEP(b13.y, a13.y) CLS_STEP(b14.x, a14.x)     \
    CLS_STEP(b14.y, a14.y)                                                   \
    float d0 = sx - T0, d1 = sy - T1, d2 = sw - T2v, d3 = sh - T3;           \
    float dc = pc - 1.0f;                                                    \
    r = d0 * d0 + d1 * d1 + d2 * d2 + d3 * d3 + 2.0f * dc * dc;

#define CLS_STEP(tv, pv) { float v_ = (tv); if (v_ > best) { best = v_; pc = (pv); } }

__device__ __forceinline__ void row_compute_vals(
    float2 a0, float2 a1, float2 a2, float2 a3, float2 a4,
    float2 a5, float2 a6, float2 a7, float2 a8, float2 a9,
    float2 a10, float2 a11, float2 a12, float2 a13, float2 a14,
    float2 b0, float2 b1, float2 b2, float2 b3, float2 b4,
    float2 b5, float2 b6, float2 b7, float2 b8, float2 b9,
    float2 b10, float2 b11, float2 b12, float2 b13, float2 b14,
    bool& coord, float& r, float& noo)
{
    ROW_MATH_BODY
}

// Plain-C++ row load+compute (used only in K2's boundary fixup).
__device__ __forceinline__ void row_load_compute(
    const float* __restrict__ gp, const float* __restrict__ gt, long row,
    bool& coord, float& r, float& noo)
{
    const float2* P2 = (const float2*)(gp + row * (long)COLS);
    const float2* T2 = (const float2*)(gt + row * (long)COLS);
    float2 a0 = P2[0],  a1 = P2[1],  a2 = P2[2],  a3 = P2[3],  a4 = P2[4];
    float2 a5 = P2[5],  a6 = P2[6],  a7 = P2[7],  a8 = P2[8],  a9 = P2[9];
    float2 a10 = P2[10], a11 = P2[11], a12 = P2[12], a13 = P2[13], a14 = P2[14];
    float2 b0 = T2[0],  b1 = T2[1],  b2 = T2[2],  b3 = T2[3],  b4 = T2[4];
    float2 b5 = T2[5],  b6 = T2[6],  b7 = T2[7],  b8 = T2[8],  b9 = T2[9];
    float2 b10 = T2[10], b11 = T2[11], b12 = T2[12], b13 = T2[13], b14 = T2[14];
    ROW_MATH_BODY
}

#define F2(v, c0, c1) make_float2((v).c0, (v).c1)

// K1: 2 rows/thread. One asm block: 30 global_load_dwordx4 (15 per tensor,
// 240 B/thread) + s_waitcnt vmcnt(0). 15 line-requests per row (was 30).
__global__ __launch_bounds__(256, 2) void yolo_k1(const float* __restrict__ gp,
                                                  const float* __restrict__ gt,
                                                  int* __restrict__ cnt,
                                                  float* __restrict__ sumR,
                                                  float* __restrict__ noo) {
    __shared__ float wr[4], wn[4];
    __shared__ int wc[4];
    int tid = threadIdx.x;
    long pair = (long)blockIdx.x * 256 + tid;          // 2 rows per pair
    unsigned int voff = (unsigned int)(pair * 240l);   // byte offset (16B-mult)

    float4 f0, f1, f2, f3, f4, f5, f6, f7, f8, f9, f10, f11, f12, f13, f14;
    float4 g0, g1, g2, g3, g4, g5, g6, g7, g8, g9, g10, g11, g12, g13, g14;
    asm volatile(
        "global_load_dwordx4 %0,  %[off], %[pb]\n\t"
        "global_load_dwordx4 %1,  %[off], %[pb] offset:16\n\t"
        "global_load_dwordx4 %2,  %[off], %[pb] offset:32\n\t"
        "global_load_dwordx4 %3,  %[off], %[pb] offset:48\n\t"
        "global_load_dwordx4 %4,  %[off], %[pb] offset:64\n\t"
        "global_load_dwordx4 %5,  %[off], %[pb] offset:80\n\t"
        "global_load_dwordx4 %6,  %[off], %[pb] offset:96\n\t"
        "global_load_dwordx4 %7,  %[off], %[pb] offset:112\n\t"
        "global_load_dwordx4 %8,  %[off], %[pb] offset:128\n\t"
        "global_load_dwordx4 %9,  %[off], %[pb] offset:144\n\t"
        "global_load_dwordx4 %10, %[off], %[pb] offset:160\n\t"
        "global_load_dwordx4 %11, %[off], %[pb] offset:176\n\t"
        "global_load_dwordx4 %12, %[off], %[pb] offset:192\n\t"
        "global_load_dwordx4 %13, %[off], %[pb] offset:208\n\t"
        "global_load_dwordx4 %14, %[off], %[pb] offset:224\n\t"
        "global_load_dwordx4 %15, %[off], %[tb]\n\t"
        "global_load_dwordx4 %16, %[off], %[tb] offset:16\n\t"
        "global_load_dwordx4 %17, %[off], %[tb] offset:32\n\t"
        "global_load_dwordx4 %18, %[off], %[tb] offset:48\n\t"
        "global_load_dwordx4 %19, %[off], %[tb] offset:64\n\t"
        "global_load_dwordx4 %20, %[off], %[tb] offset:80\n\t"
        "global_load_dwordx4 %21, %[off], %[tb] offset:96\n\t"
        "global_load_dwordx4 %22, %[off], %[tb] offset:112\n\t"
        "global_load_dwordx4 %23, %[off], %[tb] offset:128\n\t"
        "global_load_dwordx4 %24, %[off], %[tb] offset:144\n\t"
        "global_load_dwordx4 %25, %[off], %[tb] offset:160\n\t"
        "global_load_dwordx4 %26, %[off], %[tb] offset:176\n\t"
        "global_load_dwordx4 %27, %[off], %[tb] offset:192\n\t"
        "global_load_dwordx4 %28, %[off], %[tb] offset:208\n\t"
        "global_load_dwordx4 %29, %[off], %[tb] offset:224\n\t"
        "s_waitcnt vmcnt(0)"
        : "=v"(f0), "=v"(f1), "=v"(f2), "=v"(f3), "=v"(f4),
          "=v"(f5), "=v"(f6), "=v"(f7), "=v"(f8), "=v"(f9),
          "=v"(f10), "=v"(f11), "=v"(f12), "=v"(f13), "=v"(f14),
          "=v"(g0), "=v"(g1), "=v"(g2), "=v"(g3), "=v"(g4),
          "=v"(g5), "=v"(g6), "=v"(g7), "=v"(g8), "=v"(g9),
          "=v"(g10), "=v"(g11), "=v"(g12), "=v"(g13), "=v"(g14)
        : [off]"v"(voff), [pb]"s"(gp), [tb]"s"(gt)
        : "memory");

    // Row A = floats 0..29 of the 60-float chunk; row B = floats 30..59.
    bool cA, cB; float rA, rB, nA, nB;
    row_compute_vals(F2(f0,x,y), F2(f0,z,w), F2(f1,x,y), F2(f1,z,w), F2(f2,x,y),
                     F2(f2,z,w), F2(f3,x,y), F2(f3,z,w), F2(f4,x,y), F2(f4,z,w),
                     F2(f5,x,y), F2(f5,z,w), F2(f6,x,y), F2(f6,z,w), F2(f7,x,y),
                     F2(g0,x,y), F2(g0,z,w), F2(g1,x,y), F2(g1,z,w), F2(g2,x,y),
                     F2(g2,z,w), F2(g3,x,y), F2(g3,z,w), F2(g4,x,y), F2(g4,z,w),
                     F2(g5,x,y), F2(g5,z,w), F2(g6,x,y), F2(g6,z,w), F2(g7,x,y),
                     cA, rA, nA);
    row_compute_vals(F2(f7,z,w), F2(f8,x,y), F2(f8,z,w), F2(f9,x,y), F2(f9,z,w),
                     F2(f10,x,y), F2(f10,z,w), F2(f11,x,y), F2(f11,z,w), F2(f12,x,y),
                     F2(f12,z,w), F2(f13,x,y), F2(f13,z,w), F2(f14,x,y), F2(f14,z,w),
                     F2(g7,z,w), F2(g8,x,y), F2(g8,z,w), F2(g9,x,y), F2(g9,z,w),
                     F2(g10,x,y), F2(g10,z,w), F2(g11,x,y), F2(g11,z,w), F2(g12,x,y),
                     F2(g12,z,w), F2(g13,x,y), F2(g13,z,w), F2(g14,x,y), F2(g14,z,w),
                     cB, rB, nB);

    float rl = (cA ? rA : 0.0f) + (cB ? rB : 0.0f);
    float nt = nA + nB;
    int c = (int)__popcll(__ballot(cA)) + (int)__popcll(__ballot(cB));
#pragma unroll
    for (int off = 32; off > 0; off >>= 1) {
        rl += __shfl_down(rl, off);
        nt += __shfl_down(nt, off);
    }
    int wave = tid >> 6, lane = tid & 63;
    if (lane == 0) { wr[wave] = rl; wn[wave] = nt; wc[wave] = c; }
    __syncthreads();
    if (tid == 0) {
        cnt[blockIdx.x]  = wc[0] + wc[1] + wc[2] + wc[3];
        sumR[blockIdx.x] = wr[0] + wr[1] + wr[2] + wr[3];
        noo[blockIdx.x]  = wn[0] + wn[1] + wn[2] + wn[3];
    }
}

// K2: totals + scan + boundary-block (512 rows) fixup, single block.
__global__ __launch_bounds__(256) void yolo_k2(const int* __restrict__ cnt,
                                               const float* __restrict__ sumR,
                                               const float* __restrict__ noo,
                                               const float* __restrict__ gp,
                                               const float* __restrict__ gt,
                                               float* __restrict__ out) {
    __shared__ int   wsum[4];
    __shared__ float wf[4], wn2[4];
    __shared__ int   s_bstar, s_kstar;
    __shared__ float s_base;
    __shared__ int   s_wcnt[4];
    int tid = threadIdx.x;
    int lane = tid & 63, wave = tid >> 6;
    if (tid == 0) { s_bstar = -1; s_kstar = 0; }

    const int PER = 7;                  // 256*7 = 1792 >= 1568
    int start = tid * PER;
    int end = min(NB, start + PER);

    int cloc = 0; float nloc = 0.0f;
    for (int i = start; i < end; ++i) { cloc += cnt[i]; nloc += noo[i]; }

    int incl = cloc;                    // inclusive shfl scan within wave
#pragma unroll
    for (int off = 1; off < 64; off <<= 1) {
        int v = __shfl_up(incl, off);
        if (lane >= off) incl += v;
    }
    if (lane == 63) wsum[wave] = incl;
    __syncthreads();                    // also orders s_bstar init vs walk
    int woff = 0;
#pragma unroll
    for (int w = 0; w < 4; ++w) woff += (w < wave) ? wsum[w] : 0;
    int ex = woff + incl - cloc;        // exclusive global prefix
    int n_obj = wsum[0] + wsum[1] + wsum[2] + wsum[3];
    int n_half = n_obj >> 1;

    float acc = 0.0f;
    int running = ex;
    for (int i = start; i < end; ++i) {
        int ci = cnt[i];
        if (ci > 0) {
            if (running + ci <= n_half) {
                acc += sumR[i];
            } else if (running < n_half) {  // exactly one thread ever
                s_bstar = i;
                s_kstar = n_half - running;
            }
        }
        running += ci;
    }

#pragma unroll
    for (int off = 32; off > 0; off >>= 1) {
        acc  += __shfl_down(acc, off);
        nloc += __shfl_down(nloc, off);
    }
    if (lane == 0) { wf[wave] = acc; wn2[wave] = nloc; }
    __syncthreads();
    if (tid == 0)
        s_base = 5.0f * (wf[0] + wf[1] + wf[2] + wf[3])
               + 0.5f * (wn2[0] + wn2[1] + wn2[2] + wn2[3]);
    __syncthreads();

    // Phase B: boundary block (512 rows, 2 rows/thread, interleaved ranks:
    // thread tid covers in-block rows 2*tid (A) and 2*tid+1 (B)).
    int bstar = s_bstar, kstar = s_kstar;
    float total = 0.0f;
    if (bstar >= 0) {                    // uniform branch
        long rowA = (long)bstar * 512 + 2 * tid;
        bool cA, cB; float rA, rB, nA, nB;
        row_load_compute(gp, gt, rowA, cA, rA, nA);
        row_load_compute(gp, gt, rowA + 1, cB, rB, nB);
        unsigned long long balA = __ballot(cA);
        unsigned long long balB = __ballot(cB);
        if (lane == 0)
            s_wcnt[wave] = (int)__popcll(balA) + (int)__popcll(balB);
        __syncthreads();
        int waveoff = 0;
#pragma unroll
        for (int w = 0; w < 4; ++w) waveoff += (w < wave) ? s_wcnt[w] : 0;
        unsigned long long lemask =
            (lane == 63) ? ~0ull : ((1ull << (lane + 1)) - 1ull);
        unsigned long long ltmask = (1ull << lane) - 1ull;
        // wave-local order: A0 B0 A1 B1 ... (lane l = rows 2l, 2l+1)
        int rankA = waveoff + (int)__popcll(balA & lemask)
                            + (int)__popcll(balB & ltmask);
        int rankB = waveoff + (int)__popcll(balA & lemask)
                            + (int)__popcll(balB & lemask);
        float val = ((cA && rankA <= kstar) ? rA : 0.0f)
                  + ((cB && rankB <= kstar) ? rB : 0.0f);
#pragma unroll
        for (int off = 32; off > 0; off >>= 1) val += __shfl_down(val, off);
        if (lane == 0) wf[wave] = val;
        __syncthreads();
        if (tid == 0) total = wf[0] + wf[1] + wf[2] + wf[3];
    }
    if (tid == 0) out[0] = s_base + 5.0f * total;
}

extern "C" void kernel_launch(void* const* d_in, const int* in_sizes, int n_in,
                              void* d_out, int out_size, void* d_ws, size_t ws_size,
                              hipStream_t stream) {
    (void)in_sizes; (void)n_in; (void)out_size; (void)ws_size;
    const float* p = (const float*)d_in[0];   // predictions
    const float* t = (const float*)d_in[1];   // targets
    char* ws = (char*)d_ws;                   // ~19 KB used
    int*   cnt  = (int*)ws;
    float* sumR = (float*)(ws + (size_t)NB * 4);
    float* noo  = (float*)(ws + (size_t)NB * 8);
    float* out  = (float*)d_out;

    yolo_k1<<<NB, 256, 0, stream>>>(p, t, cnt, sumR, noo);
    yolo_k2<<<1, 256, 0, stream>>>(cnt, sumR, noo, p, t, out);
}